// Round 2
// baseline (148.671 us; speedup 1.0000x reference)
//
#include <hip/hip_runtime.h>
#include <math.h>

// Problem constants
#define BATCH 64
#define SEQL  512
#define DIN   256
#define NF    256
#define KS    3
#define KF    (KS * NF)        // 768

// Combined-channel formulation, fully fused:
//   Xcat[lp,ch] (lp = l+1 local, rows lbase-1..lbase+128):
//     ch<256 -> bf16(x[b,l,ch]) ; ch>=256 -> Y[b,l,ch-256] = (x@U)*sigmoid(z)
//   out[b,l,f] = relu( sum_{k,ch} Xcat[l+k-1][ch] * WcT[f][k*512+ch] + bias[f] )
// One block = (b, 128-row slab). Xcat lives entirely in LDS (4 panels of
// [130][128] bf16); Y is computed in-block by MFMA (halo rows recomputed,
// 3% redundancy). No intermediate global tensor.
#define XCH 512
#define KC  (KS * XCH)          // 1536
#define PROWS 130               // 128 out rows + 2 halo
#define PLD   128               // panel row stride (shorts) = 256 B
#define PSZ   (PROWS * PLD)     // 16640 shorts per panel

typedef __attribute__((ext_vector_type(8))) short short8;
typedef __attribute__((ext_vector_type(4))) float floatx4;
typedef __attribute__((ext_vector_type(8))) unsigned short ushort8v;

static __device__ __forceinline__ unsigned short f2bf(float f) {
    unsigned int u = __float_as_uint(f);
    return (unsigned short)((u + 0x7FFF + ((u >> 16) & 1)) >> 16);  // RTNE
}

// async 16B/lane global->LDS; LDS dst = wave-uniform base + lane*16
static __device__ __forceinline__ void gl_lds16(const void* g, void* l) {
    __builtin_amdgcn_global_load_lds(
        (const __attribute__((address_space(1))) unsigned int*)g,
        (__attribute__((address_space(3))) unsigned int*)l, 16, 0, 0);
}

// ---------------------------------------------------------------------------
// pack: WcT[f][c] transpose (96 blk), UT[e][d] transpose (16 blk).
// 112 blocks x 256 threads. (No Xc tensor anymore.)
// ---------------------------------------------------------------------------
__global__ __launch_bounds__(256) void pack_kernel(
    const float* __restrict__ U, const float* __restrict__ V,
    const float* __restrict__ Bw,
    unsigned short* __restrict__ WcT, unsigned short* __restrict__ UT)
{
    const int blk = blockIdx.x;
    const int t   = threadIdx.x;
    __shared__ unsigned short tile[64][64 + 2];

    if (blk < 96) {
        const int f0 = (blk & 3) * 64, c0 = (blk >> 2) * 64;
        const int fl = t & 63, cb = t >> 6;
        #pragma unroll
        for (int it = 0; it < 16; ++it) {
            const int cl = cb + it * 4;
            const int c  = c0 + cl;
            const int k  = c >> 9, ch = c & (XCH - 1);
            const float v = (ch < DIN) ? Bw[(size_t)ch * KF + k * NF + f0 + fl]
                                       : V[(size_t)(ch - DIN) * KF + k * NF + f0 + fl];
            tile[cl][fl] = f2bf(v);
        }
        __syncthreads();
        const int cl2 = t & 63, fb = t >> 6;
        #pragma unroll
        for (int it = 0; it < 16; ++it) {
            const int fl2 = fb + it * 4;
            WcT[(size_t)(f0 + fl2) * KC + c0 + cl2] = tile[cl2][fl2];
        }
    } else {
        const int bb = blk - 96;
        const int e0 = (bb & 3) * 64, d0 = (bb >> 2) * 64;
        const int el = t & 63, db = t >> 6;
        #pragma unroll
        for (int it = 0; it < 16; ++it) {
            const int dl = db + it * 4;
            tile[dl][el] = f2bf(U[(size_t)(d0 + dl) * DIN + e0 + el]);
        }
        __syncthreads();
        const int dl2 = t & 63, eb = t >> 6;
        #pragma unroll
        for (int it = 0; it < 16; ++it) {
            const int el2 = eb + it * 4;
            UT[(size_t)(e0 + el2) * DIN + d0 + dl2] = tile[dl2][el2];
        }
    }
}

// ---------------------------------------------------------------------------
// fused: per block (b, 128-row slab):
//   phase X: stage x rows lbase-1..lbase+128 as bf16 -> panels P0 (ch 0..127),
//            P1 (ch 128..255). 16-B units XOR-swizzled by (row&15).
//   phase G: Y[row][e] = sum_d x[row][d]*UT[e][d], two e-halves of 128;
//            per half: 4 K-chunks of 64 staged from UT into Bs (16 KB);
//            epilogue scales by sigmoid(z) and writes P2 (e 0..127) / P3.
//   phase C: conv GEMM, two f-halves of 128; per (fh,g,k,hh) region stage
//            Bs = WcT[128 f][64 ch] and accumulate 16 MFMA/wave.
// LDS = 4*33.3 KB panels + 16 KB Bs = 146 KB -> 1 block/CU, 8 waves.
// Grid 256 x 512.
// ---------------------------------------------------------------------------
__global__ __launch_bounds__(512, 2) void fused_kernel(
    const float* __restrict__ x, const float* __restrict__ z,
    const unsigned short* __restrict__ UT,
    const unsigned short* __restrict__ WcT,
    const float* __restrict__ bias, float* __restrict__ out)
{
    __shared__ unsigned short lds[4 * PSZ + 128 * 64];   // 149.5 KB
    unsigned short* Bs = lds + 4 * PSZ;

    const int tid  = threadIdx.x;
    const int lane = tid & 63;
    const int wave = tid >> 6;
    const int quad = lane >> 4, l16 = lane & 15;
    const int r8   = lane >> 3, ud8 = lane & 7;

    const int bid   = blockIdx.x;
    const int b     = bid >> 2;
    const int lbase = (bid & 3) * 128;

    // ---------------- phase X: x -> P0, P1 (bf16, swizzled) ----------------
    #pragma unroll 1
    for (int p = 0; p < 2; ++p) {
        unsigned short* P = lds + p * PSZ;
        #pragma unroll
        for (int it = 0; it < 5; ++it) {
            const int idx = tid + it * 512;
            if (idx < PROWS * 16) {
                const int row = idx >> 4, u = idx & 15;
                const int l = lbase - 1 + row;
                ushort8v h = {};
                if (l >= 0 && l < SEQL) {
                    const float* xp = x + ((size_t)b * SEQL + l) * DIN + p * 128 + u * 8;
                    const float4 v0 = *(const float4*)xp;
                    const float4 v1 = *(const float4*)(xp + 4);
                    h[0] = f2bf(v0.x); h[1] = f2bf(v0.y);
                    h[2] = f2bf(v0.z); h[3] = f2bf(v0.w);
                    h[4] = f2bf(v1.x); h[5] = f2bf(v1.y);
                    h[6] = f2bf(v1.z); h[7] = f2bf(v1.w);
                }
                *(ushort8v*)&P[row * PLD + ((u ^ (row & 15)) << 3)] = h;
            }
        }
    }
    __syncthreads();

    // ---------------- phase G: Y = (x@U)*sigmoid(z) -> P2, P3 --------------
    #pragma unroll 1
    for (int eh = 0; eh < 2; ++eh) {
        floatx4 accY[9] = {};
        #pragma unroll 1
        for (int kk = 0; kk < 4; ++kk) {   // K-chunk of 64 d (panel kk>>1, half kk&1)
            const unsigned short* gU = UT + (size_t)(eh * 128) * DIN + kk * 64;
            #pragma unroll
            for (int c = 0; c < 2; ++c) {
                const int r = wave * 16 + c * 8 + r8;
                gl_lds16(gU + (size_t)r * DIN + (ud8 ^ (r & 7)) * 8,
                         Bs + (size_t)(wave * 16 + c * 8) * 64);
            }
            __syncthreads();
            const unsigned short* P = lds + (kk >> 1) * PSZ;
            const int dh = kk & 1;
            #pragma unroll
            for (int ks = 0; ks < 2; ++ks) {
                const short8 bf = *(const short8*)
                    &Bs[(wave * 16 + l16) * 64 + (((ks * 4 + quad) ^ (l16 & 7)) * 8)];
                #pragma unroll
                for (int i = 0; i < 9; ++i) {
                    const short8 af = *(const short8*)
                        &P[(i * 16 + l16) * PLD +
                           (((dh * 8 + ks * 4 + quad) ^ (l16 & 15)) * 8)];
                    accY[i] = __builtin_amdgcn_mfma_f32_16x16x32_bf16(
                        af, bf, accY[i], 0, 0, 0);
                }
            }
            __syncthreads();
        }
        // epilogue: scale + bf16 + swizzled scatter into P(2+eh)
        const int ecol = wave * 16 + l16;                  // 0..127
        const float zf = 1.0f /
            (1.0f + expf(-z[(size_t)b * DIN + eh * 128 + ecol]));
        unsigned short* PY = lds + (2 + eh) * PSZ;
        const int u16e = ecol >> 3;
        #pragma unroll
        for (int i = 0; i < 9; ++i) {
            #pragma unroll
            for (int r = 0; r < 4; ++r) {
                const int row = i * 16 + quad * 4 + r;
                if (row < PROWS)
                    PY[row * PLD + ((u16e ^ (row & 15)) << 3) + (ecol & 7)] =
                        f2bf(accY[i][r] * zf);
            }
        }
    }
    __syncthreads();

    // ---------------- phase C: conv over 4 panels x 3 taps -----------------
    const int wr = wave & 3;          // 32-row chunk
    const int wc = wave >> 2;         // 64-f chunk
    #pragma unroll 1
    for (int fh = 0; fh < 2; ++fh) {
        floatx4 acc[2][4] = {};
        #pragma unroll 1
        for (int g = 0; g < 4; ++g) {
            const unsigned short* P = lds + g * PSZ;
            #pragma unroll 1
            for (int k = 0; k < KS; ++k) {
                #pragma unroll 1
                for (int hh = 0; hh < 2; ++hh) {
                    const unsigned short* gW =
                        WcT + (size_t)(fh * 128) * KC + k * XCH + g * 128 + hh * 64;
                    #pragma unroll
                    for (int c = 0; c < 2; ++c) {
                        const int r = wave * 16 + c * 8 + r8;
                        gl_lds16(gW + (size_t)r * KC + (ud8 ^ (r & 7)) * 8,
                                 Bs + (size_t)(wave * 16 + c * 8) * 64);
                    }
                    __syncthreads();
                    #pragma unroll
                    for (int ks = 0; ks < 2; ++ks) {
                        short8 af[2], bfr[4];
                        #pragma unroll
                        for (int i = 0; i < 2; ++i) {
                            const int row = wr * 32 + i * 16 + l16 + k;
                            af[i] = *(const short8*)
                                &P[row * PLD +
                                   (((hh * 8 + ks * 4 + quad) ^ (row & 15)) * 8)];
                        }
                        #pragma unroll
                        for (int j = 0; j < 4; ++j) {
                            const int n = wc * 64 + j * 16 + l16;
                            bfr[j] = *(const short8*)
                                &Bs[n * 64 + (((ks * 4 + quad) ^ (n & 7)) * 8)];
                        }
                        #pragma unroll
                        for (int i = 0; i < 2; ++i)
                            #pragma unroll
                            for (int j = 0; j < 4; ++j)
                                acc[i][j] = __builtin_amdgcn_mfma_f32_16x16x32_bf16(
                                    af[i], bfr[j], acc[i][j], 0, 0, 0);
                    }
                    __syncthreads();
                }
            }
        }
        // out: bias + relu, f32 stores (16 consecutive f per l16 group)
        #pragma unroll
        for (int j = 0; j < 4; ++j) {
            const int f  = fh * 128 + wc * 64 + j * 16 + l16;
            const float bv = bias[f];
            #pragma unroll
            for (int i = 0; i < 2; ++i) {
                const int lrow = lbase + wr * 32 + i * 16 + quad * 4;
                #pragma unroll
                for (int r = 0; r < 4; ++r) {
                    const float v = acc[i][j][r] + bv;
                    out[((size_t)b * SEQL + lrow + r) * NF + f] = fmaxf(v, 0.0f);
                }
            }
        }
    }
}

extern "C" void kernel_launch(void* const* d_in, const int* in_sizes, int n_in,
                              void* d_out, int out_size, void* d_ws, size_t ws_size,
                              hipStream_t stream) {
    const float* x    = (const float*)d_in[0];
    const float* z    = (const float*)d_in[1];
    const float* U    = (const float*)d_in[2];
    const float* V    = (const float*)d_in[3];
    const float* Bw   = (const float*)d_in[4];
    const float* bias = (const float*)d_in[5];

    unsigned short* WcT = (unsigned short*)d_ws;          // 256*1536*2 B
    unsigned short* UT  = WcT + (size_t)NF * KC;          // 256*256*2 B
    float* out = (float*)d_out;

    pack_kernel<<<dim3(112), 256, 0, stream>>>(U, V, Bw, WcT, UT);
    fused_kernel<<<dim3(256), 512, 0, stream>>>(x, z, UT, WcT, bias, out);
}

// Round 3
// 129.311 us; speedup vs baseline: 1.1497x; 1.1497x over previous
//
#include <hip/hip_runtime.h>
#include <math.h>

// Problem constants
#define BATCH 64
#define SEQL  512
#define DIN   256
#define NF    256
#define KS    3
#define KF    (KS * NF)        // 768

// Combined-channel formulation, fully fused:
//   Xcat[lp,ch] (lp local, rows lbase-1..lbase+128):
//     ch<256 -> bf16(x[b,l,ch]) ; ch>=256 -> Y[b,l,ch-256] = (x@U)*sigmoid(z)
//   out[b,l,f] = relu( sum_{k,ch} Xcat[l+k-1][ch] * WcT[f][k*512+ch] + bias[f] )
// One block = (b, 128-row slab). Xcat in LDS (4 panels [130][128] bf16).
// Conv uses 32x32x16 MFMA, 64x64 wave tiles (8 waves = 2 wr x 4 wc over
// 128 rows x 256 f). All B-staging double-buffered in DEAD panel space:
//   conv g=0,1 (x panels live):  Bs dbuf in P2/P3 space (2 x 32 KB)
//   phase G    (x panels live):  UT dbuf in P3 tail     (2 x 16 KB)
//   conv g=2,3 (Y panels live):  Bs dbuf in P0/P1 space (2 x 32 KB)
// Stage issued BEFORE compute each region (T3-minimum) so the barrier's
// vmcnt(0) drain hits an already-landed load. LDS total 133 KB.
#define XCH 512
#define KC  (KS * XCH)          // 1536
#define PROWS 130               // 128 out rows + 2 halo
#define PLD   128               // panel row stride (shorts) = 256 B
#define PSZ   (PROWS * PLD)     // 16640 shorts per panel

typedef __attribute__((ext_vector_type(8))) short short8;
typedef __attribute__((ext_vector_type(4))) float floatx4;
typedef __attribute__((ext_vector_type(16))) float floatx16;
typedef __attribute__((ext_vector_type(8))) unsigned short ushort8v;

static __device__ __forceinline__ unsigned short f2bf(float f) {
    unsigned int u = __float_as_uint(f);
    return (unsigned short)((u + 0x7FFF + ((u >> 16) & 1)) >> 16);  // RTNE
}

// async 16B/lane global->LDS; LDS dst = wave-uniform base + lane*16
static __device__ __forceinline__ void gl_lds16(const void* g, void* l) {
    __builtin_amdgcn_global_load_lds(
        (const __attribute__((address_space(1))) unsigned int*)g,
        (__attribute__((address_space(3))) unsigned int*)l, 16, 0, 0);
}

// ---------------------------------------------------------------------------
// pack: WcT[f][c] transpose (96 blk), UT[e][d] transpose (16 blk).
// 112 blocks x 256 threads.
// ---------------------------------------------------------------------------
__global__ __launch_bounds__(256) void pack_kernel(
    const float* __restrict__ U, const float* __restrict__ V,
    const float* __restrict__ Bw,
    unsigned short* __restrict__ WcT, unsigned short* __restrict__ UT)
{
    const int blk = blockIdx.x;
    const int t   = threadIdx.x;
    __shared__ unsigned short tile[64][64 + 2];

    if (blk < 96) {
        const int f0 = (blk & 3) * 64, c0 = (blk >> 2) * 64;
        const int fl = t & 63, cb = t >> 6;
        #pragma unroll
        for (int it = 0; it < 16; ++it) {
            const int cl = cb + it * 4;
            const int c  = c0 + cl;
            const int k  = c >> 9, ch = c & (XCH - 1);
            const float v = (ch < DIN) ? Bw[(size_t)ch * KF + k * NF + f0 + fl]
                                       : V[(size_t)(ch - DIN) * KF + k * NF + f0 + fl];
            tile[cl][fl] = f2bf(v);
        }
        __syncthreads();
        const int cl2 = t & 63, fb = t >> 6;
        #pragma unroll
        for (int it = 0; it < 16; ++it) {
            const int fl2 = fb + it * 4;
            WcT[(size_t)(f0 + fl2) * KC + c0 + cl2] = tile[cl2][fl2];
        }
    } else {
        const int bb = blk - 96;
        const int e0 = (bb & 3) * 64, d0 = (bb >> 2) * 64;
        const int el = t & 63, db = t >> 6;
        #pragma unroll
        for (int it = 0; it < 16; ++it) {
            const int dl = db + it * 4;
            tile[dl][el] = f2bf(U[(size_t)(d0 + dl) * DIN + e0 + el]);
        }
        __syncthreads();
        const int dl2 = t & 63, eb = t >> 6;
        #pragma unroll
        for (int it = 0; it < 16; ++it) {
            const int el2 = eb + it * 4;
            UT[(size_t)(e0 + el2) * DIN + d0 + dl2] = tile[dl2][el2];
        }
    }
}

// ---------------------------------------------------------------------------
// fused kernel. Grid 256 x 512. LDS 133.1 KB -> 1 block/CU (8 waves).
// ---------------------------------------------------------------------------
__global__ __launch_bounds__(512, 2) void fused_kernel(
    const float* __restrict__ x, const float* __restrict__ z,
    const unsigned short* __restrict__ UT,
    const unsigned short* __restrict__ WcT,
    const float* __restrict__ bias, float* __restrict__ out)
{
    __shared__ __align__(16) unsigned short lds[4 * PSZ];   // 133120 B

    const int tid  = threadIdx.x;
    const int lane = tid & 63;
    const int wave = tid >> 6;
    const int quad = lane >> 4, l16 = lane & 15;
    const int l32  = lane & 31, hi  = lane >> 5;
    const int r8   = lane >> 3, ud8 = lane & 7;

    const int bid   = blockIdx.x;
    const int b     = bid >> 2;
    const int lbase = (bid & 3) * 128;

    const int wr = wave >> 2, wc = wave & 3;   // conv: 2x4 grid of 64x64 tiles

    // conv accumulators: 2x2 of 32x32 tiles = 64 VGPR, live whole kernel
    floatx16 acc[2][2] = {};

    // B-staging buffer for conv region r (24 regions: r = (g*3+k)*2+hh):
    //   r<12 (g=0,1): dbuf in P2/P3 space; r>=12 (g=2,3): dbuf in P0/P1 space
    auto convBuf = [&](int r) -> unsigned short* {
        return (r < 12) ? (lds + 2 * PSZ + ((r & 1) ? 16384 : 0))
                        : (lds + ((r & 1) ? PSZ : 0));
    };
    // stage WcT block [256 f][64 ch] for region r (4 gl_lds16/wave)
    auto stageB = [&](int r) {
        unsigned short* buf = convBuf(r);
        const int g = r / 6, k = (r / 2) % 3, hh = r & 1;
        const unsigned short* gW = WcT + (size_t)k * XCH + g * 128 + hh * 64;
        #pragma unroll
        for (int c = 0; c < 4; ++c) {
            const int rr = wave * 32 + c * 8 + r8;
            gl_lds16(gW + (size_t)rr * KC + ((ud8 ^ (rr & 7)) << 3),
                     buf + (size_t)(wave * 32 + c * 8) * 64);
        }
    };
    // conv compute for region r: 4 k-slices x (af[2]+bf[2] -> 4 MFMA 32x32x16)
    auto convRegion = [&](int r) {
        const unsigned short* buf = convBuf(r);
        const int g = r / 6, k = (r / 2) % 3, hh = r & 1;
        const unsigned short* P = lds + (size_t)g * PSZ;
        #pragma unroll
        for (int ks = 0; ks < 4; ++ks) {
            short8 af[2], bf[2];
            const int uwa = hh * 8 + ks * 2 + hi;
            #pragma unroll
            for (int i = 0; i < 2; ++i) {
                const int m = wr * 64 + i * 32 + l32 + k;
                af[i] = *(const short8*)&P[m * PLD + ((uwa ^ (m & 15)) << 3)];
            }
            const int uwb = ks * 2 + hi;
            #pragma unroll
            for (int j = 0; j < 2; ++j) {
                const int n = wc * 64 + j * 32 + l32;
                bf[j] = *(const short8*)&buf[n * 64 + ((uwb ^ (n & 7)) << 3)];
            }
            #pragma unroll
            for (int i = 0; i < 2; ++i)
                #pragma unroll
                for (int j = 0; j < 2; ++j)
                    acc[i][j] = __builtin_amdgcn_mfma_f32_32x32x16_bf16(
                        af[i], bf[j], acc[i][j], 0, 0, 0);
        }
    };

    // ---------------- phase X: x -> P0, P1 (bf16, swizzled) ----------------
    #pragma unroll 1
    for (int p = 0; p < 2; ++p) {
        unsigned short* P = lds + (size_t)p * PSZ;
        #pragma unroll
        for (int it = 0; it < 5; ++it) {
            const int idx = tid + it * 512;
            if (idx < PROWS * 16) {
                const int row = idx >> 4, u = idx & 15;
                const int l = lbase - 1 + row;
                ushort8v h = {};
                if (l >= 0 && l < SEQL) {
                    const float* xp = x + ((size_t)b * SEQL + l) * DIN + p * 128 + u * 8;
                    const float4 v0 = *(const float4*)xp;
                    const float4 v1 = *(const float4*)(xp + 4);
                    h[0] = f2bf(v0.x); h[1] = f2bf(v0.y);
                    h[2] = f2bf(v0.z); h[3] = f2bf(v0.w);
                    h[4] = f2bf(v1.x); h[5] = f2bf(v1.y);
                    h[6] = f2bf(v1.z); h[7] = f2bf(v1.w);
                }
                *(ushort8v*)&P[row * PLD + ((u ^ (row & 15)) << 3)] = h;
            }
        }
    }

    // ---------------- conv part A: g = 0,1 (x panels), regions 0..11 -------
    stageB(0);
    __syncthreads();                       // X writes visible + stage(0) landed
    #pragma unroll 1
    for (int r = 0; r < 12; ++r) {
        if (r < 11) stageB(r + 1);         // issue-early: hides under compute
        convRegion(r);
        __syncthreads();
    }

    // ---------------- phase G: Y = (x@U)*sigmoid(z) -> P2, P3 --------------
    {
        floatx4 accY[9] = {};
        auto utBuf = [&](int rg) -> unsigned short* {
            return lds + 3 * PSZ + ((rg & 1) ? 8192 : 0);   // P3 tail space
        };
        auto stageU = [&](int rg) {
            unsigned short* buf = utBuf(rg);
            const int eh = rg >> 2, kk = rg & 3;
            const unsigned short* gU = UT + (size_t)(eh * 128) * DIN + kk * 64;
            #pragma unroll
            for (int c = 0; c < 2; ++c) {
                const int rr = wave * 16 + c * 8 + r8;
                gl_lds16(gU + (size_t)rr * DIN + ((ud8 ^ (rr & 7)) << 3),
                         buf + (size_t)(wave * 16 + c * 8) * 64);
            }
        };
        stageU(0);
        __syncthreads();
        #pragma unroll 1
        for (int rg = 0; rg < 8; ++rg) {
            if (rg < 7) stageU(rg + 1);
            const unsigned short* buf = utBuf(rg);
            const int kk = rg & 3;
            const unsigned short* P = lds + (size_t)(kk >> 1) * PSZ;
            const int dh = kk & 1;
            #pragma unroll
            for (int ks = 0; ks < 2; ++ks) {
                const short8 bfv = *(const short8*)
                    &buf[(wave * 16 + l16) * 64 + (((ks * 4 + quad) ^ (l16 & 7)) << 3)];
                #pragma unroll
                for (int i = 0; i < 9; ++i) {
                    const int row = i * 16 + l16;   // rows >=130 read garbage, masked below
                    const short8 afv = *(const short8*)
                        &P[row * PLD + (((dh * 8 + ks * 4 + quad) ^ (row & 15)) << 3)];
                    accY[i] = __builtin_amdgcn_mfma_f32_16x16x32_bf16(
                        afv, bfv, accY[i], 0, 0, 0);
                }
            }
            if (rg == 3) {
                // epilogue eh=0 -> P2 panel (P2 space dead: old conv-A Bs)
                const int ecol = wave * 16 + l16;
                const float zf = 1.0f / (1.0f + expf(-z[(size_t)b * DIN + ecol]));
                unsigned short* PY = lds + 2 * PSZ;
                const int u16e = ecol >> 3;
                #pragma unroll
                for (int i = 0; i < 9; ++i)
                    #pragma unroll
                    for (int rr2 = 0; rr2 < 4; ++rr2) {
                        const int row = i * 16 + quad * 4 + rr2;
                        if (row < PROWS)
                            PY[row * PLD + ((u16e ^ (row & 15)) << 3) + (ecol & 7)] =
                                f2bf(accY[i][rr2] * zf);
                    }
                #pragma unroll
                for (int i = 0; i < 9; ++i)
                    #pragma unroll
                    for (int rr2 = 0; rr2 < 4; ++rr2)
                        accY[i][rr2] = 0.0f;
            }
            __syncthreads();
        }
        // epilogue eh=1 -> P3 panel. AFTER final barrier (P3 space held the
        // UT dbuf; all waves' reads of it are complete here).
        {
            const int ecol = wave * 16 + l16;
            const float zf = 1.0f / (1.0f + expf(-z[(size_t)b * DIN + 128 + ecol]));
            unsigned short* PY = lds + 3 * PSZ;
            const int u16e = ecol >> 3;
            #pragma unroll
            for (int i = 0; i < 9; ++i)
                #pragma unroll
                for (int rr2 = 0; rr2 < 4; ++rr2) {
                    const int row = i * 16 + quad * 4 + rr2;
                    if (row < PROWS)
                        PY[row * PLD + ((u16e ^ (row & 15)) << 3) + (ecol & 7)] =
                            f2bf(accY[i][rr2] * zf);
                }
        }
    }

    // ---------------- conv part B: g = 2,3 (Y panels), regions 12..23 ------
    // Bs dbuf now in P0/P1 space (x panels dead after phase G).
    stageB(12);
    __syncthreads();                       // drains eh=1 epilogue ds_writes too
    #pragma unroll 1
    for (int r = 12; r < 24; ++r) {
        if (r < 23) stageB(r + 1);
        convRegion(r);
        __syncthreads();
    }

    // ---------------- epilogue: bias + relu -> out -------------------------
    #pragma unroll
    for (int j = 0; j < 2; ++j) {
        const int f  = wc * 64 + j * 32 + l32;
        const float bv = bias[f];
        #pragma unroll
        for (int i = 0; i < 2; ++i) {
            #pragma unroll
            for (int reg = 0; reg < 16; ++reg) {
                const int rowl = wr * 64 + i * 32 + (reg & 3) + 8 * (reg >> 2) + 4 * hi;
                const float v = acc[i][j][reg] + bv;
                out[((size_t)b * SEQL + lbase + rowl) * NF + f] = fmaxf(v, 0.0f);
            }
        }
    }
}

extern "C" void kernel_launch(void* const* d_in, const int* in_sizes, int n_in,
                              void* d_out, int out_size, void* d_ws, size_t ws_size,
                              hipStream_t stream) {
    const float* x    = (const float*)d_in[0];
    const float* z    = (const float*)d_in[1];
    const float* U    = (const float*)d_in[2];
    const float* V    = (const float*)d_in[3];
    const float* Bw   = (const float*)d_in[4];
    const float* bias = (const float*)d_in[5];

    unsigned short* WcT = (unsigned short*)d_ws;          // 256*1536*2 B
    unsigned short* UT  = WcT + (size_t)NF * KC;          // 256*256*2 B
    float* out = (float*)d_out;

    pack_kernel<<<dim3(112), 256, 0, stream>>>(U, V, Bw, WcT, UT);
    fused_kernel<<<dim3(256), 512, 0, stream>>>(x, z, UT, WcT, bias, out);
}

// Round 5
// 128.378 us; speedup vs baseline: 1.1581x; 1.0073x over previous
//
#include <hip/hip_runtime.h>
#include <math.h>

// Problem constants
#define BATCH 64
#define SEQL  512
#define DIN   256
#define NF    256
#define KS    3
#define KF    (KS * NF)        // 768

// Combined-channel formulation, fully fused:
//   Xcat[lp,ch] (lp local, rows lbase-1..lbase+128):
//     ch<256 -> bf16(x[b,l,ch]) ; ch>=256 -> Y[b,l,ch-256] = (x@U)*sigmoid(z)
//   out[b,l,f] = relu( sum_{k,ch} Xcat[l+k-1][ch] * WcT[f][k*512+ch] + bias[f] )
// One block = (b, 128-row slab). Xcat in LDS (4 panels [130][128] bf16).
// Conv: 32x32x16 MFMA, 64x64 wave tiles (8 waves = 2 wr x 4 wc).
// All staging double-buffered in DEAD panel space, issued BEFORE compute
// (T3-minimum) so barriers drain already-landed loads:
//   conv g=0,1 (x panels live):  Bs dbuf in P2/P3 space (2 x 32 KB)
//   phase G    (x panels live):  UT dbuf in P2/P3 space (2 x 32 KB, [256e][64d])
//   conv g=2,3 (Y panels live):  Bs dbuf in P0/P1 space (2 x 32 KB)
// Phase G single K-sweep computes BOTH e-halves (accY[2][9]) so x-panels are
// read once, not twice. s_setprio(1) wraps MFMA clusters (T5).
#define XCH 512
#define KC  (KS * XCH)          // 1536
#define PROWS 130               // 128 out rows + 2 halo
#define PLD   128               // panel row stride (shorts) = 256 B
#define PSZ   (PROWS * PLD)     // 16640 shorts per panel

typedef __attribute__((ext_vector_type(8))) short short8;
typedef __attribute__((ext_vector_type(4))) float floatx4;
typedef __attribute__((ext_vector_type(16))) float floatx16;
typedef __attribute__((ext_vector_type(8))) unsigned short ushort8v;

static __device__ __forceinline__ unsigned short f2bf(float f) {
    unsigned int u = __float_as_uint(f);
    return (unsigned short)((u + 0x7FFF + ((u >> 16) & 1)) >> 16);  // RTNE
}

// async 16B/lane global->LDS; LDS dst = wave-uniform base + lane*16
static __device__ __forceinline__ void gl_lds16(const void* g, void* l) {
    __builtin_amdgcn_global_load_lds(
        (const __attribute__((address_space(1))) unsigned int*)g,
        (__attribute__((address_space(3))) unsigned int*)l, 16, 0, 0);
}

// ---------------------------------------------------------------------------
// pack: WcT[f][c] transpose (96 blk), UT[e][d] transpose (16 blk).
// 112 blocks x 256 threads.
// ---------------------------------------------------------------------------
__global__ __launch_bounds__(256) void pack_kernel(
    const float* __restrict__ U, const float* __restrict__ V,
    const float* __restrict__ Bw,
    unsigned short* __restrict__ WcT, unsigned short* __restrict__ UT)
{
    const int blk = blockIdx.x;
    const int t   = threadIdx.x;
    __shared__ unsigned short tile[64][64 + 2];

    if (blk < 96) {
        const int f0 = (blk & 3) * 64, c0 = (blk >> 2) * 64;
        const int fl = t & 63, cb = t >> 6;
        #pragma unroll
        for (int it = 0; it < 16; ++it) {
            const int cl = cb + it * 4;
            const int c  = c0 + cl;
            const int k  = c >> 9, ch = c & (XCH - 1);
            const float v = (ch < DIN) ? Bw[(size_t)ch * KF + k * NF + f0 + fl]
                                       : V[(size_t)(ch - DIN) * KF + k * NF + f0 + fl];
            tile[cl][fl] = f2bf(v);
        }
        __syncthreads();
        const int cl2 = t & 63, fb = t >> 6;
        #pragma unroll
        for (int it = 0; it < 16; ++it) {
            const int fl2 = fb + it * 4;
            WcT[(size_t)(f0 + fl2) * KC + c0 + cl2] = tile[cl2][fl2];
        }
    } else {
        const int bb = blk - 96;
        const int e0 = (bb & 3) * 64, d0 = (bb >> 2) * 64;
        const int el = t & 63, db = t >> 6;
        #pragma unroll
        for (int it = 0; it < 16; ++it) {
            const int dl = db + it * 4;
            tile[dl][el] = f2bf(U[(size_t)(d0 + dl) * DIN + e0 + el]);
        }
        __syncthreads();
        const int dl2 = t & 63, eb = t >> 6;
        #pragma unroll
        for (int it = 0; it < 16; ++it) {
            const int el2 = eb + it * 4;
            UT[(size_t)(e0 + el2) * DIN + d0 + dl2] = tile[dl2][el2];
        }
    }
}

// ---------------------------------------------------------------------------
// fused kernel. Grid 256 x 512. LDS 133.1 KB -> 1 block/CU (8 waves).
// ---------------------------------------------------------------------------
__global__ __launch_bounds__(512, 2) void fused_kernel(
    const float* __restrict__ x, const float* __restrict__ z,
    const unsigned short* __restrict__ UT,
    const unsigned short* __restrict__ WcT,
    const float* __restrict__ bias, float* __restrict__ out)
{
    __shared__ __align__(16) unsigned short lds[4 * PSZ];   // 133120 B

    const int tid  = threadIdx.x;
    const int lane = tid & 63;
    const int wave = tid >> 6;
    const int quad = lane >> 4, l16 = lane & 15;
    const int l32  = lane & 31, hi  = lane >> 5;
    const int r8   = lane >> 3, ud8 = lane & 7;

    const int bid   = blockIdx.x;
    const int b     = bid >> 2;
    const int lbase = (bid & 3) * 128;

    const int wr = wave >> 2, wc = wave & 3;   // conv: 2x4 grid of 64x64 tiles

    // conv accumulators: 2x2 of 32x32 tiles = 64 VGPR, live whole kernel
    floatx16 acc[2][2] = {};

    // B-staging buffer for conv region r (24 regions: r = (g*3+k)*2+hh):
    //   r<12 (g=0,1): dbuf in P2/P3 space; r>=12 (g=2,3): dbuf in P0/P1 space
    auto convBuf = [&](int r) -> unsigned short* {
        return (r < 12) ? (lds + 2 * PSZ + ((r & 1) ? 16384 : 0))
                        : (lds + ((r & 1) ? PSZ : 0));
    };
    // stage WcT block [256 f][64 ch] for region r (4 gl_lds16/wave)
    auto stageB = [&](int r) {
        unsigned short* buf = convBuf(r);
        const int g = r / 6, k = (r / 2) % 3, hh = r & 1;
        const unsigned short* gW = WcT + (size_t)k * XCH + g * 128 + hh * 64;
        #pragma unroll
        for (int c = 0; c < 4; ++c) {
            const int rr = wave * 32 + c * 8 + r8;
            gl_lds16(gW + (size_t)rr * KC + ((ud8 ^ (rr & 7)) << 3),
                     buf + (size_t)(wave * 32 + c * 8) * 64);
        }
    };
    // conv compute for region r: 4 k-slices x (af[2]+bf[2] -> 4 MFMA 32x32x16)
    auto convRegion = [&](int r) {
        const unsigned short* buf = convBuf(r);
        const int g = r / 6, k = (r / 2) % 3, hh = r & 1;
        const unsigned short* P = lds + (size_t)g * PSZ;
        __builtin_amdgcn_s_setprio(1);
        #pragma unroll
        for (int ks = 0; ks < 4; ++ks) {
            short8 af[2], bf[2];
            const int uwa = hh * 8 + ks * 2 + hi;
            #pragma unroll
            for (int i = 0; i < 2; ++i) {
                const int m = wr * 64 + i * 32 + l32 + k;
                af[i] = *(const short8*)&P[m * PLD + ((uwa ^ (m & 15)) << 3)];
            }
            const int uwb = ks * 2 + hi;
            #pragma unroll
            for (int j = 0; j < 2; ++j) {
                const int n = wc * 64 + j * 32 + l32;
                bf[j] = *(const short8*)&buf[n * 64 + ((uwb ^ (n & 7)) << 3)];
            }
            #pragma unroll
            for (int i = 0; i < 2; ++i)
                #pragma unroll
                for (int j = 0; j < 2; ++j)
                    acc[i][j] = __builtin_amdgcn_mfma_f32_32x32x16_bf16(
                        af[i], bf[j], acc[i][j], 0, 0, 0);
        }
        __builtin_amdgcn_s_setprio(0);
    };

    // ---------------- phase X: x -> P0, P1 (bf16, swizzled) ----------------
    // Fully unrolled so all global loads issue before the ds_writes (T14).
    #pragma unroll
    for (int p = 0; p < 2; ++p) {
        unsigned short* P = lds + (size_t)p * PSZ;
        #pragma unroll
        for (int it = 0; it < 5; ++it) {
            const int idx = tid + it * 512;
            if (idx < PROWS * 16) {
                const int row = idx >> 4, u = idx & 15;
                const int l = lbase - 1 + row;
                ushort8v h = {};
                if (l >= 0 && l < SEQL) {
                    const float* xp = x + ((size_t)b * SEQL + l) * DIN + p * 128 + u * 8;
                    const float4 v0 = *(const float4*)xp;
                    const float4 v1 = *(const float4*)(xp + 4);
                    h[0] = f2bf(v0.x); h[1] = f2bf(v0.y);
                    h[2] = f2bf(v0.z); h[3] = f2bf(v0.w);
                    h[4] = f2bf(v1.x); h[5] = f2bf(v1.y);
                    h[6] = f2bf(v1.z); h[7] = f2bf(v1.w);
                }
                *(ushort8v*)&P[row * PLD + ((u ^ (row & 15)) << 3)] = h;
            }
        }
    }

    // ---------------- conv part A: g = 0,1 (x panels), regions 0..11 -------
    stageB(0);
    __syncthreads();                       // X writes visible + stage(0) landed
    #pragma unroll 1
    for (int r = 0; r < 12; ++r) {
        if (r < 11) stageB(r + 1);         // issue-early: hides under compute
        convRegion(r);
        __syncthreads();
    }

    // ---------------- phase G: Y = (x@U)*sigmoid(z) -> P2, P3 --------------
    // Single K-sweep over 4 kk-chunks of 64 d; BOTH e-halves per sweep
    // (accY[2][9]) so x-panels are read once. UT staged [256 e][64 d]
    // (32 KB), dbuf'd in P2/P3 dead space.
    {
        floatx4 accY[2][9] = {};
        auto utBuf = [&](int kk) -> unsigned short* {
            return lds + 2 * PSZ + ((kk & 1) ? 16384 : 0);
        };
        auto stageU = [&](int kk) {
            unsigned short* buf = utBuf(kk);
            const unsigned short* gU = UT + (size_t)kk * 64;
            #pragma unroll
            for (int c = 0; c < 4; ++c) {
                const int rr = wave * 32 + c * 8 + r8;
                gl_lds16(gU + (size_t)rr * DIN + ((ud8 ^ (rr & 7)) << 3),
                         buf + (size_t)(wave * 32 + c * 8) * 64);
            }
        };
        stageU(0);
        __syncthreads();
        #pragma unroll 1
        for (int kk = 0; kk < 4; ++kk) {
            if (kk < 3) stageU(kk + 1);
            const unsigned short* buf = utBuf(kk);
            const unsigned short* P = lds + (size_t)(kk >> 1) * PSZ;
            const int dh = kk & 1;
            __builtin_amdgcn_s_setprio(1);
            #pragma unroll
            for (int ks = 0; ks < 2; ++ks) {
                short8 bfv[2];
                #pragma unroll
                for (int eh = 0; eh < 2; ++eh) {
                    const int n = eh * 128 + wave * 16 + l16;
                    bfv[eh] = *(const short8*)
                        &buf[n * 64 + (((ks * 4 + quad) ^ (n & 7)) << 3)];
                }
                #pragma unroll
                for (int i = 0; i < 9; ++i) {
                    const int row = i * 16 + l16;   // rows >=130 garbage, masked below
                    const short8 afv = *(const short8*)
                        &P[row * PLD + (((dh * 8 + ks * 4 + quad) ^ (row & 15)) << 3)];
                    #pragma unroll
                    for (int eh = 0; eh < 2; ++eh)
                        accY[eh][i] = __builtin_amdgcn_mfma_f32_16x16x32_bf16(
                            afv, bfv[eh], accY[eh][i], 0, 0, 0);
                }
            }
            __builtin_amdgcn_s_setprio(0);
            __syncthreads();
        }
        // epilogues: scale + bf16 + swizzled scatter into P2 (eh=0), P3 (eh=1).
        // P2/P3 space held the UT dbuf; all reads of it completed at the
        // final barrier above.
        #pragma unroll
        for (int eh = 0; eh < 2; ++eh) {
            const int ecol = wave * 16 + l16;
            const float zf = 1.0f /
                (1.0f + expf(-z[(size_t)b * DIN + eh * 128 + ecol]));
            unsigned short* PY = lds + (size_t)(2 + eh) * PSZ;
            const int u16e = ecol >> 3;
            #pragma unroll
            for (int i = 0; i < 9; ++i)
                #pragma unroll
                for (int rr2 = 0; rr2 < 4; ++rr2) {
                    const int row = i * 16 + quad * 4 + rr2;
                    if (row < PROWS)
                        PY[row * PLD + ((u16e ^ (row & 15)) << 3) + (ecol & 7)] =
                            f2bf(accY[eh][i][rr2] * zf);
                }
        }
    }

    // ---------------- conv part B: g = 2,3 (Y panels), regions 12..23 ------
    // Bs dbuf now in P0/P1 space (x panels dead after phase G).
    stageB(12);
    __syncthreads();                       // drains Y-epilogue ds_writes too
    #pragma unroll 1
    for (int r = 12; r < 24; ++r) {
        if (r < 23) stageB(r + 1);
        convRegion(r);
        __syncthreads();
    }

    // ---------------- epilogue: bias + relu -> out -------------------------
    #pragma unroll
    for (int j = 0; j < 2; ++j) {
        const int f  = wc * 64 + j * 32 + l32;
        const float bv = bias[f];
        #pragma unroll
        for (int i = 0; i < 2; ++i) {
            #pragma unroll
            for (int reg = 0; reg < 16; ++reg) {
                const int rowl = wr * 64 + i * 32 + (reg & 3) + 8 * (reg >> 2) + 4 * hi;
                const float v = acc[i][j][reg] + bv;
                out[((size_t)b * SEQL + lbase + rowl) * NF + f] = fmaxf(v, 0.0f);
            }
        }
    }
}

extern "C" void kernel_launch(void* const* d_in, const int* in_sizes, int n_in,
                              void* d_out, int out_size, void* d_ws, size_t ws_size,
                              hipStream_t stream) {
    const float* x    = (const float*)d_in[0];
    const float* z    = (const float*)d_in[1];
    const float* U    = (const float*)d_in[2];
    const float* V    = (const float*)d_in[3];
    const float* Bw   = (const float*)d_in[4];
    const float* bias = (const float*)d_in[5];

    unsigned short* WcT = (unsigned short*)d_ws;          // 256*1536*2 B
    unsigned short* UT  = WcT + (size_t)NF * KC;          // 256*256*2 B
    float* out = (float*)d_out;

    pack_kernel<<<dim3(112), 256, 0, stream>>>(U, V, Bw, WcT, UT);
    fused_kernel<<<dim3(256), 512, 0, stream>>>(x, z, UT, WcT, bias, out);
}